// Round 9
// baseline (724.032 us; speedup 1.0000x reference)
//
#include <hip/hip_runtime.h>

// B=2,S=2048 -> T=4096 tokens, D=1024, F=4096, E=8; top_k on device.
// fp32 I/O; bf16 MFMA compute (fp32 accumulate).
// R14: R13's verified 2-phase machinery, geometry 256Mx128N BK=32
// (8 waves as 2Mx4N, 2x24KB LDS buffers, 2 blocks/CU). Halves B-side
// global traffic per FLOP and improves LDS-read:MFMA ratio. build_work
// at 256-row tiles. Router/transposes identical to R13.
#define T_TOK 4096
#define DIM   1024
#define FDIM  4096
#define NEXP  8
#define BUFSZ 24576

typedef __bf16 bf16x8 __attribute__((ext_vector_type(8)));
typedef __bf16 bf16x4 __attribute__((ext_vector_type(4)));
typedef float  f32x4  __attribute__((ext_vector_type(4)));
typedef const __attribute__((address_space(3))) char* lds3;

__device__ __forceinline__ void glds16(const void* g, void* l) {
    __builtin_amdgcn_global_load_lds(
        (const __attribute__((address_space(1))) void*)g,
        (__attribute__((address_space(3))) void*)l, 16, 0, 0);
}

// Clobber-free (R9/R10 lesson): no "memory" clobber => no compiler-inserted
// vmcnt drains before the reads; data ordering via lgkmcnt(0)+sched_barrier.
#define DSR(dst, a, imm) \
    asm volatile("ds_read_b128 %0, %1 offset:" #imm : "=v"(dst) : "v"(a))

// Bijective XCD-chunking swizzle (m204).
__device__ __forceinline__ int xcd_swz(int phys, int total) {
    int q = total >> 3, r = total & 7;
    int x = phys & 7, i = phys >> 3;
    return (x < r ? x * (q + 1) : r * (q + 1) + (x - r) * q) + i;
}

// ---------------------------------------------------------------------------
// Router (+ x->bf16 convert): one wave per token.
// ---------------------------------------------------------------------------
__global__ __launch_bounds__(64)
void moe_router(const float* __restrict__ x,
                const float* __restrict__ gw,
                const float* __restrict__ gb,
                const int*   __restrict__ topk_p,
                int*   __restrict__ counts,
                int*   __restrict__ bucket,
                float* __restrict__ bweight,
                __bf16* __restrict__ xb) {
    const int t = blockIdx.x;
    const int lane = threadIdx.x;
    float part[NEXP];
#pragma unroll
    for (int e = 0; e < NEXP; ++e) part[e] = 0.f;
    const float* xrow = x + (size_t)t * DIM;
    __bf16* xbrow = xb + (size_t)t * DIM;
#pragma unroll
    for (int r = 0; r < 4; ++r) {
        int c = r * 256 + lane * 4;
        float4 v = *(const float4*)&xrow[c];
        bf16x4 o; o[0]=(__bf16)v.x; o[1]=(__bf16)v.y; o[2]=(__bf16)v.z; o[3]=(__bf16)v.w;
        *(bf16x4*)&xbrow[c] = o;
#pragma unroll
        for (int e = 0; e < NEXP; ++e) {
            float4 g = *(const float4*)&gw[e * DIM + c];
            part[e] += v.x*g.x + v.y*g.y + v.z*g.z + v.w*g.w;
        }
    }
#pragma unroll
    for (int off = 32; off > 0; off >>= 1) {
#pragma unroll
        for (int e = 0; e < NEXP; ++e) part[e] += __shfl_xor(part[e], off);
    }
    if (lane == 0) {
        int k = topk_p[0];
        if (k < 1) k = 1;
        if (k > NEXP) k = NEXP;
        float p[NEXP];
        float mx = -1e30f;
#pragma unroll
        for (int e = 0; e < NEXP; ++e) {
            p[e] = part[e] + gb[e];
            mx = fmaxf(mx, p[e]);
        }
#pragma unroll
        for (int e = 0; e < NEXP; ++e) p[e] = __expf(p[e] - mx);
        bool used[NEXP];
#pragma unroll
        for (int e = 0; e < NEXP; ++e) used[e] = false;
        int sel[NEXP]; float selp[NEXP]; float wsum = 0.f;
        for (int j = 0; j < k; ++j) {
            int best = 0; float bv = -1.f;
            for (int e = 0; e < NEXP; ++e)
                if (!used[e] && p[e] > bv) { bv = p[e]; best = e; }  // ties->low idx
            used[best] = true; sel[j] = best; selp[j] = bv; wsum += bv;
        }
        for (int j = 0; j < k; ++j) {
            int e = sel[j];
            int pos = atomicAdd(&counts[e], 1);
            bucket[e * T_TOK + pos]  = t;
            bweight[e * T_TOK + pos] = selp[j] / wsum;
        }
    }
}

// ---------------------------------------------------------------------------
// Transpose+convert: in [z][R][C] fp32 -> out [z][C][R] bf16.
// Tile: 128 R-rows x 64 C-cols; 256B read and write segments.
// ---------------------------------------------------------------------------
__global__ __launch_bounds__(256)
void transpose_cvt(const float* __restrict__ in, __bf16* __restrict__ out,
                   int R, int C) {
    const size_t zo = (size_t)blockIdx.z * R * C;
    in += zo; out += zo;
    __shared__ float ts[64][129];
    const int r0 = blockIdx.x * 128, c0 = blockIdx.y * 64;
    const int t = threadIdx.x;
    const int rr = t >> 4;            // 0..15 row within pass
    const int cl = (t & 15) * 4;      // float4 col within 64
    float4 v[8];
#pragma unroll
    for (int p = 0; p < 8; ++p)
        v[p] = *(const float4*)&in[(size_t)(r0 + p * 16 + rr) * C + c0 + cl];
#pragma unroll
    for (int p = 0; p < 8; ++p) {
        ts[cl + 0][p * 16 + rr] = v[p].x;
        ts[cl + 1][p * 16 + rr] = v[p].y;
        ts[cl + 2][p * 16 + rr] = v[p].z;
        ts[cl + 3][p * 16 + rr] = v[p].w;
    }
    __syncthreads();
    const int oc = t >> 4;            // 0..15 c-row within pass
    const int orc = (t & 15) * 8;     // 8-elem chunk within 128
#pragma unroll
    for (int p = 0; p < 4; ++p) {
        bf16x8 o;
#pragma unroll
        for (int j = 0; j < 8; ++j) o[j] = (__bf16)ts[p * 16 + oc][orc + j];
        *(bf16x8*)&out[(size_t)(c0 + p * 16 + oc) * R + r0 + orc] = o;
    }
}

// ---------------------------------------------------------------------------
// Work list: one list of (e, tile256) entries; hdr[0]=n, entries at hdr+8.
// ---------------------------------------------------------------------------
__global__ __launch_bounds__(64)
void build_work(const int* __restrict__ counts, int* __restrict__ hdr) {
    __shared__ int off1[NEXP + 1];
    const int lane = threadIdx.x;
    if (lane == 0) {
        int a = 0;
        for (int e = 0; e < NEXP; ++e) {
            off1[e] = a;
            a += (counts[e] + 255) >> 8;
        }
        off1[NEXP] = a;
        hdr[0] = a;
    }
    __syncthreads();
    for (int e = 0; e < NEXP; ++e) {
        int n1 = off1[e + 1] - off1[e];
        for (int j = lane; j < n1; j += 64) hdr[8 + off1[e] + j] = (e << 16) | j;
    }
}

// ---------------------------------------------------------------------------
// 2-phase GEMM machinery, 256Mx128N BK=32, 8 waves (2M x 4N).
// Buffer (24KB): A[256 rows][32 elems] at 0 (row=64B), B[128][32] at 16384.
// K-step: STAGE(next buf, 3 glds/wave) -> 10 asm ds_read_b128 (cur) ->
// lgkmcnt(0) -> 16 MFMA (setprio) -> __syncthreads.
// ---------------------------------------------------------------------------
#define STAGE(DST, KO) do { \
    glds16(pA0 + (KO), (DST) + wave * 1024); \
    glds16(pA1 + (KO), (DST) + 8192 + wave * 1024); \
    glds16(pB0 + (KO), (DST) + 16384 + wave * 1024); } while (0)

#define PHASE(APTR, BPTR) do { \
    bf16x8 af[8], bfr[2]; \
    DSR(af[0], (APTR), 0);    DSR(af[1], (APTR), 1024); \
    DSR(af[2], (APTR), 2048); DSR(af[3], (APTR), 3072); \
    DSR(af[4], (APTR), 4096); DSR(af[5], (APTR), 5120); \
    DSR(af[6], (APTR), 6144); DSR(af[7], (APTR), 7168); \
    DSR(bfr[0], (BPTR), 0);   DSR(bfr[1], (BPTR), 1024); \
    asm volatile("s_waitcnt lgkmcnt(0)"); \
    __builtin_amdgcn_sched_barrier(0); \
    __builtin_amdgcn_s_setprio(1); \
    _Pragma("unroll") for (int i_ = 0; i_ < 8; ++i_) \
    _Pragma("unroll") for (int j_ = 0; j_ < 2; ++j_) \
        acc[i_][j_] = __builtin_amdgcn_mfma_f32_16x16x32_bf16( \
            af[i_], bfr[j_], acc[i_][j_], 0, 0, 0); \
    __builtin_amdgcn_s_setprio(0); \
    __builtin_amdgcn_sched_barrier(0); \
    __syncthreads(); } while (0)

#define KLOOP2(NT) do { \
    STAGE(stg0, 0); \
    __syncthreads(); \
    _Pragma("unroll 1") \
    for (int t_ = 0; t_ < (NT); t_ += 2) { \
        STAGE(stg1, (t_ + 1) * 32); \
        PHASE(aP0, bP0); \
        if (t_ + 2 < (NT)) STAGE(stg0, (t_ + 2) * 32); \
        PHASE(aP1, bP1); \
    } } while (0)

#define GEMM_LANES \
    const int tid = threadIdx.x; \
    const int wave = tid >> 6, lane = tid & 63; \
    const int wm = wave >> 2, wn = wave & 3;   /* 2M x 4N */ \
    const int quad = lane >> 4, l15 = lane & 15; \
    const int lrow = lane >> 2; \
    const int lk8  = (lane & 3) * 8; \
    const int srow = (wave << 4) + lrow;       /* staging row 0..127 */ \
    char* stg0 = sb; \
    char* stg1 = sb + BUFSZ; \
    lds3 s3 = (lds3)sb; \
    lds3 aP0 = s3 + (wm * 128 + l15) * 64 + quad * 16; \
    lds3 bP0 = s3 + 16384 + (wn * 32 + l15) * 64 + quad * 16; \
    lds3 aP1 = aP0 + BUFSZ; \
    lds3 bP1 = bP0 + BUFSZ;

// ---------------------------------------------------------------------------
// GEMM1: H[e,pos,f] = silu( xb[tok].W1T[e][f][:] + b1[e][f] )  256Mx128N
// ---------------------------------------------------------------------------
__global__ __launch_bounds__(512, 4)
void moe_gemm1(const __bf16* __restrict__ xb,
               const __bf16* __restrict__ w1t,   // [E][F][D]
               const float*  __restrict__ b1,
               const int*    __restrict__ counts,
               const int*    __restrict__ bucket,
               const int*    __restrict__ hdr,
               __bf16* __restrict__ H) {
    __shared__ __align__(16) char sb[2 * BUFSZ];   // 48KB
    __shared__ int tok_s[256];
    GEMM_LANES

    const int n1 = hdr[0];
    const int total = n1 * (FDIM / 128);
    for (int phys = blockIdx.x; phys < total; phys += gridDim.x) {
        const int u = xcd_swz(phys, total);
        const int entry = hdr[8 + (u % n1)];
        const int e = entry >> 16, tile = entry & 0xffff;
        const int nb = (u / n1) * 128;
        const int cnt = counts[e];
        if (tid < 256) {
            int r = tile * 256 + tid;
            if (r >= cnt) r = cnt - 1;
            tok_s[tid] = bucket[e * T_TOK + r];
        }
        __syncthreads();

        const __bf16* pA0 = xb + (size_t)tok_s[srow]       * DIM + lk8;
        const __bf16* pA1 = xb + (size_t)tok_s[srow + 128] * DIM + lk8;
        const __bf16* pB0 = w1t + ((size_t)e * FDIM + nb + srow) * DIM + lk8;

        f32x4 acc[8][2];
#pragma unroll
        for (int i = 0; i < 8; ++i)
#pragma unroll
            for (int j = 0; j < 2; ++j) acc[i][j] = (f32x4){0.f,0.f,0.f,0.f};

        KLOOP2(DIM / 32);   // 32 K-steps

        // Epilogue: wave-private LDS transpose (16 rows x 32 cols, stride 40)
        // -> bf16x8 H stores.
        __bf16* stg = (__bf16*)(sb + wave * 1280);
        const float* b1e = b1 + e * FDIM + nb + wn * 32;
#pragma unroll
        for (int i = 0; i < 8; ++i) {
#pragma unroll
            for (int j = 0; j < 2; ++j) {
                float bias = b1e[j * 16 + l15];
#pragma unroll
                for (int r = 0; r < 4; ++r) {
                    float v = acc[i][j][r] + bias;
                    float s = v / (1.f + __expf(-v));   // silu
                    stg[(quad*4 + r) * 40 + j*16 + l15] = (__bf16)s;
                }
            }
            int prow = tile * 256 + wm * 128 + i * 16 + lrow;
            if (prow < cnt) {
                bf16x8 v0 = *(const bf16x8*)&stg[lrow * 40 + (lane & 3) * 8];
                __bf16* dst = H + (size_t)(e * T_TOK + prow) * FDIM
                              + nb + wn * 32 + (lane & 3) * 8;
                *(bf16x8*)dst = v0;
            }
        }
        __syncthreads();   // protect smem/tok_s before next unit
    }
}

// ---------------------------------------------------------------------------
// GEMM2: out[tok,d] += w * ( H[e,pos,:].W2T[e][d][:] + b2[e][d] )
// 256Mx128N, BK=32, 2-way split-K.
// ---------------------------------------------------------------------------
#define KSPLIT 2
#define KHALF  (FDIM / KSPLIT)

__global__ __launch_bounds__(512, 4)
void moe_gemm2(const __bf16* __restrict__ H,
               const __bf16* __restrict__ w2t,   // [E][D][F]
               const float*  __restrict__ b2,
               const int*    __restrict__ counts,
               const int*    __restrict__ bucket,
               const float*  __restrict__ bweight,
               const int*    __restrict__ hdr,
               float* __restrict__ out) {
    __shared__ __align__(16) char sb[2 * BUFSZ];
    __shared__ int   tok_s[256];
    __shared__ float w_s[256];
    GEMM_LANES

    const int n1 = hdr[0];
    const int total = n1 * (DIM / 128) * KSPLIT;
    for (int phys = blockIdx.x; phys < total; phys += gridDim.x) {
        const int u = xcd_swz(phys, total);
        const int entry = hdr[8 + (u % n1)];
        const int e = entry >> 16, tile = entry & 0xffff;
        const int rest = u / n1;
        const int nb = (rest & 7) * 128;       // DIM/128 = 8 output blocks
        const int kc = rest >> 3;              // split-K chunk: 0 or 1
        const int cnt = counts[e];
        if (tid < 256) {
            int r  = tile * 256 + tid;
            int rc = r < cnt ? r : cnt - 1;
            tok_s[tid] = bucket[e * T_TOK + rc];
            w_s[tid]   = bweight[e * T_TOK + rc];
        }
        __syncthreads();

        // A rows (H) are contiguous positions — no gather needed.
        const size_t kbase = (size_t)kc * KHALF;
        const __bf16* pA0 = H + (size_t)(e * T_TOK + tile * 256 + srow) * FDIM
                              + kbase + lk8;
        const __bf16* pA1 = pA0 + (size_t)128 * FDIM;
        const __bf16* pB0 = w2t + ((size_t)e * DIM + nb + srow) * FDIM
                              + kbase + lk8;

        f32x4 acc[8][2];
#pragma unroll
        for (int i = 0; i < 8; ++i)
#pragma unroll
            for (int j = 0; j < 2; ++j) acc[i][j] = (f32x4){0.f,0.f,0.f,0.f};

        KLOOP2(KHALF / 32);   // 64 K-steps

#pragma unroll
        for (int i = 0; i < 8; ++i)
#pragma unroll
            for (int j = 0; j < 2; ++j)
#pragma unroll
                for (int r = 0; r < 4; ++r) {
                    int m = wm*128 + i*16 + quad*4 + r;
                    int prow = tile * 256 + m;
                    if (prow < cnt) {
                        int dc = nb + wn*32 + j*16 + l15;
                        float v = acc[i][j][r] + (kc == 0 ? b2[e * DIM + dc] : 0.f);
                        atomicAdd(&out[(size_t)tok_s[m] * DIM + dc], w_s[m] * v);
                    }
                }
        __syncthreads();   // protect tok_s/w_s before next unit
    }
}

extern "C" void kernel_launch(void* const* d_in, const int* in_sizes, int n_in,
                              void* d_out, int out_size, void* d_ws, size_t ws_size,
                              hipStream_t stream) {
    const float* x  = (const float*)d_in[0];
    const float* gw = (const float*)d_in[1];
    const float* gb = (const float*)d_in[2];
    const float* w1 = (const float*)d_in[3];
    const float* b1 = (const float*)d_in[4];
    const float* w2 = (const float*)d_in[5];
    const float* b2 = (const float*)d_in[6];
    const int* topk = (const int*)d_in[7];
    float* out = (float*)d_out;

    char* ws = (char*)d_ws;
    size_t off = 0;
    int* counts = (int*)(ws + off);    off += 256;
    int* bucket = (int*)(ws + off);    off += (size_t)NEXP * T_TOK * 4;
    float* bw   = (float*)(ws + off);  off += (size_t)NEXP * T_TOK * 4;
    int* hdr    = (int*)(ws + off);    off += 4096;
    off = (off + 255) & ~(size_t)255;
    __bf16* xb  = (__bf16*)(ws + off); off += (size_t)T_TOK * DIM * 2;        // 8MB
    __bf16* w1t = (__bf16*)(ws + off); off += (size_t)NEXP * DIM * FDIM * 2;  // 64MB
    __bf16* w2t = (__bf16*)(ws + off); off += (size_t)NEXP * FDIM * DIM * 2;  // 64MB
    __bf16* H   = (__bf16*)(ws + off);                                        // 256MB

    hipMemsetAsync(counts, 0, 256, stream);
    hipMemsetAsync(out, 0, (size_t)out_size * 4, stream);

    moe_router<<<T_TOK, 64, 0, stream>>>(x, gw, gb, topk, counts, bucket, bw, xb);
    // in [z][R][C] -> out [z][C][R]; tile 128(R) x 64(C)
    transpose_cvt<<<dim3(DIM/128, FDIM/64, NEXP), 256, 0, stream>>>(w1, w1t, DIM, FDIM);
    transpose_cvt<<<dim3(FDIM/128, DIM/64, NEXP), 256, 0, stream>>>(w2, w2t, FDIM, DIM);
    build_work<<<1, 64, 0, stream>>>(counts, hdr);

    moe_gemm1<<<1024, 512, 0, stream>>>(xb, w1t, b1, counts, bucket, hdr, H);
    moe_gemm2<<<512, 512, 0, stream>>>(H, w2t, b2, counts, bucket, bw, hdr, out);
}